// Round 5
// baseline (1492.634 us; speedup 1.0000x reference)
//
#include <hip/hip_runtime.h>
#include <hip/hip_bf16.h>
#include <cstddef>

#define B_   4
#define L_   2048
#define DM   1024
#define DI   2048
#define NST  16
#define DTR  64        // (1024+15)//16 = 64  (floor! 1039//16)
#define NBC  96        // DTR + 2*NST
#define NTOK 8192      // B_*L_

using bf16 = __hip_bfloat16;
typedef __attribute__((ext_vector_type(8))) short bf16x8;
typedef __attribute__((ext_vector_type(4))) float f32x4;

__device__ __forceinline__ float bf2f(short s) {
  unsigned u = ((unsigned)(unsigned short)s) << 16;
  float f; __builtin_memcpy(&f, &u, 4); return f;
}
__device__ __forceinline__ short f2bs(float f) {
  __hip_bfloat16 h = __float2bfloat16(f);
  short s; __builtin_memcpy(&s, &h, 2); return s;
}
__device__ __forceinline__ float sigmoidf_fast(float x) {
  return 1.f / (1.f + __expf(-x));
}

// ---------------------------------------------------------------------------
// transpose f32 in -> bf16 out, zero-pad: out[c][r] = (r<R&&c<Cc) ? in[r*lin+c] : 0
// block (32,8); grid.x covers r, grid.y covers c
// ---------------------------------------------------------------------------
__global__ __launch_bounds__(256)
void transpose_f2b(const float* __restrict__ in, short* __restrict__ out,
                   int R, int Cc, int lin, int lout)
{
  __shared__ short t[32][33];
  const int r0 = blockIdx.x * 32, c0 = blockIdx.y * 32;
  const int tx = threadIdx.x, ty = threadIdx.y;
#pragma unroll
  for (int i = 0; i < 4; i++) {
    int r = r0 + ty + i * 8;
    int c = c0 + tx;
    short v = 0;
    if (r < R && c < Cc) v = f2bs(in[(size_t)r * lin + c]);
    t[ty + i * 8][tx] = v;
  }
  __syncthreads();
#pragma unroll
  for (int i = 0; i < 4; i++) {
    int c = c0 + ty + i * 8;
    int r = r0 + tx;
    if (c < Cc && r < lout) out[(size_t)c * lout + r] = t[tx][ty + i * 8];
  }
}

// ---------------------------------------------------------------------------
// bf16 MFMA GEMM, C[M x N] = A[M x K] * Bt[N x K]^T.  128x128 tile, BK=32,
// 4 waves each 64x64 (4x4 of 16x16x32 MFMA).
// mode 0: bf16 store.  mode 1: softplus(v + bias[COL]) bf16 store.  mode 2: f32 store.
// M multiple of 128. N guarded. K multiple of 32.
// ---------------------------------------------------------------------------
__global__ __launch_bounds__(256)
void gemm_bt(const short* __restrict__ A, const short* __restrict__ Bt,
             void* __restrict__ Cv, const float* __restrict__ bias,
             int N, int K, int lda, int ldb, int ldc, int mode)
{
  __shared__ short As[128][40];   // +8 pad: 2-way-only LDS conflicts (free, m136)
  __shared__ short Bs[128][40];
  const int m0 = blockIdx.x * 128;
  const int n0 = blockIdx.y * 128;
  const int tid  = threadIdx.x;
  const int wave = tid >> 6, lane = tid & 63;
  const int wr = (wave >> 1) * 64, wc = (wave & 1) * 64;
  const int la = lane & 15, gq = lane >> 4;
  f32x4 acc[4][4] = {};

  for (int k0 = 0; k0 < K; k0 += 32) {
#pragma unroll
    for (int i = 0; i < 2; i++) {
      int idx = tid + i * 256;
      int row = idx >> 2, kc = (idx & 3) * 8;
      bf16x8 av = *(const bf16x8*)(A + (size_t)(m0 + row) * lda + k0 + kc);
      *(bf16x8*)(&As[row][kc]) = av;
      int bn = n0 + row;
      bf16x8 bv = {};
      if (bn < N) bv = *(const bf16x8*)(Bt + (size_t)bn * ldb + k0 + kc);
      *(bf16x8*)(&Bs[row][kc]) = bv;
    }
    __syncthreads();
    bf16x8 af[4], bfr[4];
#pragma unroll
    for (int i = 0; i < 4; i++) af[i]  = *(const bf16x8*)(&As[wr + i * 16 + la][gq * 8]);
#pragma unroll
    for (int j = 0; j < 4; j++) bfr[j] = *(const bf16x8*)(&Bs[wc + j * 16 + la][gq * 8]);
#pragma unroll
    for (int i = 0; i < 4; i++)
#pragma unroll
      for (int j = 0; j < 4; j++)
        acc[i][j] = __builtin_amdgcn_mfma_f32_16x16x32_bf16(af[i], bfr[j], acc[i][j], 0, 0, 0);
    __syncthreads();
  }

  // C/D layout: col = lane&15, row = (lane>>4)*4 + reg  (m89-verified)
#pragma unroll
  for (int i = 0; i < 4; i++) {
    int rowb = m0 + wr + i * 16 + gq * 4;
#pragma unroll
    for (int j = 0; j < 4; j++) {
      int col = n0 + wc + j * 16 + la;
      if (col < N) {
#pragma unroll
        for (int r = 0; r < 4; r++) {
          float v = acc[i][j][r];
          if (mode == 2) {
            ((float*)Cv)[(size_t)(rowb + r) * ldc + col] = v;
          } else {
            if (mode == 1) {
              v += bias[col];
              v = (v > 20.f) ? v : log1pf(__expf(v));
            }
            ((short*)Cv)[(size_t)(rowb + r) * ldc + col] = f2bs(v);
          }
        }
      }
    }
  }
}

// ---------------------------------------------------------------------------
// same MFMA GEMM but A is f32 (converted to bf16 during staging).  GEMM1 only.
// ---------------------------------------------------------------------------
__global__ __launch_bounds__(256)
void gemm_a32_bt(const float* __restrict__ A, const short* __restrict__ Bt,
                 short* __restrict__ C, int N, int K, int lda, int ldb, int ldc)
{
  __shared__ short As[128][40];
  __shared__ short Bs[128][40];
  const int m0 = blockIdx.x * 128;
  const int n0 = blockIdx.y * 128;
  const int tid  = threadIdx.x;
  const int wave = tid >> 6, lane = tid & 63;
  const int wr = (wave >> 1) * 64, wc = (wave & 1) * 64;
  const int la = lane & 15, gq = lane >> 4;
  f32x4 acc[4][4] = {};

  for (int k0 = 0; k0 < K; k0 += 32) {
#pragma unroll
    for (int i = 0; i < 2; i++) {
      int idx = tid + i * 256;
      int row = idx >> 2, kc = (idx & 3) * 8;
      const float* ap = A + (size_t)(m0 + row) * lda + k0 + kc;
      float4 a0 = *(const float4*)ap;
      float4 a1 = *(const float4*)(ap + 4);
      union { bf16x8 v; short h[8]; } cv;
      cv.h[0] = f2bs(a0.x); cv.h[1] = f2bs(a0.y); cv.h[2] = f2bs(a0.z); cv.h[3] = f2bs(a0.w);
      cv.h[4] = f2bs(a1.x); cv.h[5] = f2bs(a1.y); cv.h[6] = f2bs(a1.z); cv.h[7] = f2bs(a1.w);
      *(bf16x8*)(&As[row][kc]) = cv.v;
      int bn = n0 + row;
      bf16x8 bv = {};
      if (bn < N) bv = *(const bf16x8*)(Bt + (size_t)bn * ldb + k0 + kc);
      *(bf16x8*)(&Bs[row][kc]) = bv;
    }
    __syncthreads();
    bf16x8 af[4], bfr[4];
#pragma unroll
    for (int i = 0; i < 4; i++) af[i]  = *(const bf16x8*)(&As[wr + i * 16 + la][gq * 8]);
#pragma unroll
    for (int j = 0; j < 4; j++) bfr[j] = *(const bf16x8*)(&Bs[wc + j * 16 + la][gq * 8]);
#pragma unroll
    for (int i = 0; i < 4; i++)
#pragma unroll
      for (int j = 0; j < 4; j++)
        acc[i][j] = __builtin_amdgcn_mfma_f32_16x16x32_bf16(af[i], bfr[j], acc[i][j], 0, 0, 0);
    __syncthreads();
  }
#pragma unroll
  for (int i = 0; i < 4; i++) {
    int rowb = m0 + wr + i * 16 + gq * 4;
#pragma unroll
    for (int j = 0; j < 4; j++) {
      int col = n0 + wc + j * 16 + la;
      if (col < N) {
#pragma unroll
        for (int r = 0; r < 4; r++)
          C[(size_t)(rowb + r) * ldc + col] = f2bs(acc[i][j][r]);
      }
    }
  }
}

// ---------------------------------------------------------------------------
// depthwise causal conv1d (k=4) + bias + SiLU.  xz bf16 token-major (ld 4096,
// x = cols 0..2047).  one block per token, each thread covers 8 channels.
// ---------------------------------------------------------------------------
__global__ __launch_bounds__(256)
void conv_silu(const short* __restrict__ xz, const float* __restrict__ cw,
               const float* __restrict__ cb, short* __restrict__ xs)
{
  const int token = blockIdx.x;
  const int l = token & (L_ - 1);
  const int d0 = threadIdx.x * 8;

  float w[32];
#pragma unroll
  for (int i = 0; i < 8; i++) {
    float4 t = *(const float4*)(cw + (size_t)(d0 + i) * 4);
    w[i * 4 + 0] = t.x; w[i * 4 + 1] = t.y; w[i * 4 + 2] = t.z; w[i * 4 + 3] = t.w;
  }
  float acc[8];
  {
    float4 b0 = *(const float4*)(cb + d0);
    float4 b1 = *(const float4*)(cb + d0 + 4);
    acc[0] = b0.x; acc[1] = b0.y; acc[2] = b0.z; acc[3] = b0.w;
    acc[4] = b1.x; acc[5] = b1.y; acc[6] = b1.z; acc[7] = b1.w;
  }
#pragma unroll
  for (int j = 0; j < 4; j++) {
    int lj = l - 3 + j;
    if (lj >= 0) {
      bf16x8 xv = *(const bf16x8*)(xz + (size_t)(token - 3 + j) * 4096 + d0);
#pragma unroll
      for (int i = 0; i < 8; i++) acc[i] += w[i * 4 + j] * bf2f(xv[i]);
    }
  }
  union { bf16x8 v; short h[8]; } o;
#pragma unroll
  for (int i = 0; i < 8; i++) {
    float v = acc[i];
    o.h[i] = f2bs(v * sigmoidf_fast(v));
  }
  *(bf16x8*)(xs + (size_t)token * DI + d0) = o.v;
}

// ---------------------------------------------------------------------------
// selective scan, 16 lanes per (b,d) channel (one per state n), fused gating.
// delta in xz x-half (t*4096+d); res in xz res-half (t*4096+2048+d); u in xs
// (t*2048+d).  y overwrites the delta cell after consumption (single-owner,
// read-before-write in program order -> race-free).
// ---------------------------------------------------------------------------
__global__ __launch_bounds__(256)
void scan_kernel(short* __restrict__ xz, const short* __restrict__ xs,
                 const short* __restrict__ dbc,
                 const float* __restrict__ A_log, const float* __restrict__ Dw,
                 const float* __restrict__ h0)
{
  const int grp = threadIdx.x >> 4, n = threadIdx.x & 15;
  const int ch = blockIdx.x * 16 + grp;          // ch = b*DI + d
  const int b = ch >> 11, d = ch & (DI - 1);
  const float An = -__expf(A_log[d * NST + n]);
  const float Dd = Dw[d];
  float h = h0[(size_t)ch * NST + n];

  const size_t t0 = (size_t)b * L_;
  const short* bc = dbc + t0 * NBC;

  for (int l = 0; l < L_; l += 8) {
    float dts[8], us[8], rs[8];
#pragma unroll
    for (int s = 0; s < 8; s++) {
      size_t t = t0 + l + s;
      dts[s] = bf2f(xz[t * 4096 + d]);           // delta (GEMM3 output)
      rs[s]  = bf2f(xz[t * 4096 + 2048 + d]);    // res
      us[s]  = bf2f(xs[t * 2048 + d]);           // conv+silu x
    }
#pragma unroll
    for (int s = 0; s < 8; s++) {
      const short* row = bc + (size_t)(l + s) * NBC;
      float Bn = bf2f(row[DTR + n]);             // cols 64..79
      float Cn = bf2f(row[DTR + NST + n]);       // cols 80..95
      float dt = dts[s], u = us[s];
      float dA = __expf(dt * An);
      h = dA * h + (dt * u) * Bn;
      float p = h * Cn;
      p += __shfl_xor(p, 8, 16);
      p += __shfl_xor(p, 4, 16);
      p += __shfl_xor(p, 2, 16);
      p += __shfl_xor(p, 1, 16);
      if (n == 0) {
        float r = rs[s];
        float y = (p + u * Dd) * (r * sigmoidf_fast(r));
        xz[(t0 + l + s) * 4096 + d] = f2bs(y);   // y over delta cell
      }
    }
  }
}

// ---------------------------------------------------------------------------
extern "C" void kernel_launch(void* const* d_in, const int* in_sizes, int n_in,
                              void* d_out, int out_size, void* d_ws, size_t ws_size,
                              hipStream_t stream)
{
  const float* u        = (const float*)d_in[0];
  const float* hiddens  = (const float*)d_in[1];
  const float* in_proj  = (const float*)d_in[2];
  const float* conv_w   = (const float*)d_in[3];
  const float* conv_b   = (const float*)d_in[4];
  const float* x_proj   = (const float*)d_in[5];   // (2048, 96)
  const float* dt_proj  = (const float*)d_in[6];   // (64, 2048)
  const float* dt_bias  = (const float*)d_in[7];
  const float* A_log    = (const float*)d_in[8];
  const float* Dw       = (const float*)d_in[9];
  const float* out_proj = (const float*)d_in[10];
  float* out = (float*)d_out;

  // workspace: ~78 MiB total
  char* w = (char*)d_ws;
  short* Wt1  = (short*)w; w += (size_t)4096 * 1024 * 2;   // in_proj^T  (4096 x 1024)
  short* Wxp  = (short*)w; w += (size_t)96   * 2048 * 2;   // x_proj^T   (96 x 2048)
  short* dtw  = (short*)w; w += (size_t)2048 * 64   * 2;   // dt_proj^T  (2048 x 64)
  short* Wt4  = (short*)w; w += (size_t)1024 * 2048 * 2;   // out_proj^T (1024 x 2048)
  short* xz   = (short*)w; w += (size_t)NTOK * 4096 * 2;   // x|res -> delta|res -> y|res
  short* dbc  = (short*)w; w += (size_t)NTOK * NBC  * 2;   // (8192 x 96)
  short* xs   = (short*)d_out;                             // conv out borrows d_out

  dim3 tb(32, 8);
  transpose_f2b<<<dim3(32, 128), tb, 0, stream>>>(in_proj,  Wt1, 1024, 4096, 4096, 1024);
  transpose_f2b<<<dim3(64, 3),   tb, 0, stream>>>(x_proj,   Wxp, 2048, 96,   96,   2048);
  transpose_f2b<<<dim3(2, 64),   tb, 0, stream>>>(dt_proj,  dtw, 64,   2048, 2048, 64);
  transpose_f2b<<<dim3(64, 32),  tb, 0, stream>>>(out_proj, Wt4, 2048, 1024, 1024, 2048);

  // GEMM1: xz = u @ in_proj   (8192 x 4096)
  gemm_a32_bt<<<dim3(64, 32), 256, 0, stream>>>(u, Wt1, xz, 4096, 1024, 1024, 1024, 4096);
  // conv + silu -> xs (token-major, in d_out)
  conv_silu<<<NTOK, 256, 0, stream>>>(xz, conv_w, conv_b, xs);
  // GEMM2: dbc = xs @ x_proj  (8192 x 96)
  gemm_bt<<<dim3(64, 1), 256, 0, stream>>>(xs, Wxp, dbc, nullptr, 96, 2048, 2048, 2048, NBC, 0);
  // GEMM3: delta = softplus(dbc[:, :64] @ dt_proj + bias[col]) -> xz x-half (ldc 4096)
  gemm_bt<<<dim3(64, 16), 256, 0, stream>>>(dbc, dtw, xz, dt_bias, 2048, 64, NBC, 64, 4096, 1);
  // selective scan + gated epilogue: y over delta cells in xz x-half
  scan_kernel<<<512, 256, 0, stream>>>(xz, xs, dbc, A_log, Dw, hiddens);
  // GEMM4: out = y @ out_proj  (8192 x 1024, f32 store)
  gemm_bt<<<dim3(64, 8), 256, 0, stream>>>(xz, Wt4, out, nullptr, 1024, 2048, 4096, 2048, 1024, 2);
}

// Round 6
// 979.156 us; speedup vs baseline: 1.5244x; 1.5244x over previous
//
#include <hip/hip_runtime.h>
#include <hip/hip_bf16.h>
#include <cstddef>

#define B_   4
#define L_   2048
#define DM   1024
#define DI   2048
#define NST  16
#define DTR  64        // (1024+15)//16 = 64
#define NBC  96        // DTR + 2*NST
#define NTOK 8192      // B_*L_

using bf16 = __hip_bfloat16;
typedef __attribute__((ext_vector_type(8))) short bf16x8;
typedef __attribute__((ext_vector_type(4))) float f32x4;

__device__ __forceinline__ float bf2f(short s) {
  unsigned u = ((unsigned)(unsigned short)s) << 16;
  float f; __builtin_memcpy(&f, &u, 4); return f;
}
__device__ __forceinline__ short f2bs(float f) {
  __hip_bfloat16 h = __float2bfloat16(f);
  short s; __builtin_memcpy(&s, &h, 2); return s;
}
__device__ __forceinline__ float sigmoidf_fast(float x) {
  return 1.f / (1.f + __expf(-x));
}

// full-rate VALU cross-lane sum within each aligned 16-lane row (DPP row_ror)
template<int CTRL>
__device__ __forceinline__ float dpp_add(float x) {
  int v = __builtin_amdgcn_update_dpp(0, __builtin_bit_cast(int, x), CTRL, 0xf, 0xf, false);
  return x + __builtin_bit_cast(float, v);
}
__device__ __forceinline__ float rowsum16(float x) {
  x = dpp_add<0x128>(x);   // row_ror:8
  x = dpp_add<0x124>(x);   // row_ror:4
  x = dpp_add<0x122>(x);   // row_ror:2
  x = dpp_add<0x121>(x);   // row_ror:1
  return x;                // all 16 lanes hold the row sum
}

// ---------------------------------------------------------------------------
// transpose f32 in -> bf16 out, zero-pad: out[c][r] = (r<R&&c<Cc) ? in[r*lin+c] : 0
// ---------------------------------------------------------------------------
__global__ __launch_bounds__(256)
void transpose_f2b(const float* __restrict__ in, short* __restrict__ out,
                   int R, int Cc, int lin, int lout)
{
  __shared__ short t[32][33];
  const int r0 = blockIdx.x * 32, c0 = blockIdx.y * 32;
  const int tx = threadIdx.x, ty = threadIdx.y;
#pragma unroll
  for (int i = 0; i < 4; i++) {
    int r = r0 + ty + i * 8;
    int c = c0 + tx;
    short v = 0;
    if (r < R && c < Cc) v = f2bs(in[(size_t)r * lin + c]);
    t[ty + i * 8][tx] = v;
  }
  __syncthreads();
#pragma unroll
  for (int i = 0; i < 4; i++) {
    int c = c0 + ty + i * 8;
    int r = r0 + tx;
    if (c < Cc && r < lout) out[(size_t)c * lout + r] = t[tx][ty + i * 8];
  }
}

// ---------------------------------------------------------------------------
// bf16 MFMA GEMM, C[M x N] = A[M x K] * Bt[N x K]^T.  128x128 tile, BK=32,
// 4 waves each 64x64 (4x4 of 16x16x32 MFMA).
// mode 0: bf16 store.  mode 1: softplus(v + bias[COL]) bf16 store.  mode 2: f32 store.
// ---------------------------------------------------------------------------
__global__ __launch_bounds__(256)
void gemm_bt(const short* __restrict__ A, const short* __restrict__ Bt,
             void* __restrict__ Cv, const float* __restrict__ bias,
             int N, int K, int lda, int ldb, int ldc, int mode)
{
  __shared__ short As[128][40];
  __shared__ short Bs[128][40];
  const int m0 = blockIdx.x * 128;
  const int n0 = blockIdx.y * 128;
  const int tid  = threadIdx.x;
  const int wave = tid >> 6, lane = tid & 63;
  const int wr = (wave >> 1) * 64, wc = (wave & 1) * 64;
  const int la = lane & 15, gq = lane >> 4;
  f32x4 acc[4][4] = {};

  for (int k0 = 0; k0 < K; k0 += 32) {
#pragma unroll
    for (int i = 0; i < 2; i++) {
      int idx = tid + i * 256;
      int row = idx >> 2, kc = (idx & 3) * 8;
      bf16x8 av = *(const bf16x8*)(A + (size_t)(m0 + row) * lda + k0 + kc);
      *(bf16x8*)(&As[row][kc]) = av;
      int bn = n0 + row;
      bf16x8 bv = {};
      if (bn < N) bv = *(const bf16x8*)(Bt + (size_t)bn * ldb + k0 + kc);
      *(bf16x8*)(&Bs[row][kc]) = bv;
    }
    __syncthreads();
    bf16x8 af[4], bfr[4];
#pragma unroll
    for (int i = 0; i < 4; i++) af[i]  = *(const bf16x8*)(&As[wr + i * 16 + la][gq * 8]);
#pragma unroll
    for (int j = 0; j < 4; j++) bfr[j] = *(const bf16x8*)(&Bs[wc + j * 16 + la][gq * 8]);
#pragma unroll
    for (int i = 0; i < 4; i++)
#pragma unroll
      for (int j = 0; j < 4; j++)
        acc[i][j] = __builtin_amdgcn_mfma_f32_16x16x32_bf16(af[i], bfr[j], acc[i][j], 0, 0, 0);
    __syncthreads();
  }

#pragma unroll
  for (int i = 0; i < 4; i++) {
    int rowb = m0 + wr + i * 16 + gq * 4;
#pragma unroll
    for (int j = 0; j < 4; j++) {
      int col = n0 + wc + j * 16 + la;
      if (col < N) {
#pragma unroll
        for (int r = 0; r < 4; r++) {
          float v = acc[i][j][r];
          if (mode == 2) {
            ((float*)Cv)[(size_t)(rowb + r) * ldc + col] = v;
          } else {
            if (mode == 1) {
              v += bias[col];
              v = (v > 20.f) ? v : log1pf(__expf(v));
            }
            ((short*)Cv)[(size_t)(rowb + r) * ldc + col] = f2bs(v);
          }
        }
      }
    }
  }
}

// ---------------------------------------------------------------------------
// same MFMA GEMM but A is f32 (converted to bf16 during staging).  GEMM1 only.
// ---------------------------------------------------------------------------
__global__ __launch_bounds__(256)
void gemm_a32_bt(const float* __restrict__ A, const short* __restrict__ Bt,
                 short* __restrict__ C, int N, int K, int lda, int ldb, int ldc)
{
  __shared__ short As[128][40];
  __shared__ short Bs[128][40];
  const int m0 = blockIdx.x * 128;
  const int n0 = blockIdx.y * 128;
  const int tid  = threadIdx.x;
  const int wave = tid >> 6, lane = tid & 63;
  const int wr = (wave >> 1) * 64, wc = (wave & 1) * 64;
  const int la = lane & 15, gq = lane >> 4;
  f32x4 acc[4][4] = {};

  for (int k0 = 0; k0 < K; k0 += 32) {
#pragma unroll
    for (int i = 0; i < 2; i++) {
      int idx = tid + i * 256;
      int row = idx >> 2, kc = (idx & 3) * 8;
      const float* ap = A + (size_t)(m0 + row) * lda + k0 + kc;
      float4 a0 = *(const float4*)ap;
      float4 a1 = *(const float4*)(ap + 4);
      union { bf16x8 v; short h[8]; } cv;
      cv.h[0] = f2bs(a0.x); cv.h[1] = f2bs(a0.y); cv.h[2] = f2bs(a0.z); cv.h[3] = f2bs(a0.w);
      cv.h[4] = f2bs(a1.x); cv.h[5] = f2bs(a1.y); cv.h[6] = f2bs(a1.z); cv.h[7] = f2bs(a1.w);
      *(bf16x8*)(&As[row][kc]) = cv.v;
      int bn = n0 + row;
      bf16x8 bv = {};
      if (bn < N) bv = *(const bf16x8*)(Bt + (size_t)bn * ldb + k0 + kc);
      *(bf16x8*)(&Bs[row][kc]) = bv;
    }
    __syncthreads();
    bf16x8 af[4], bfr[4];
#pragma unroll
    for (int i = 0; i < 4; i++) af[i]  = *(const bf16x8*)(&As[wr + i * 16 + la][gq * 8]);
#pragma unroll
    for (int j = 0; j < 4; j++) bfr[j] = *(const bf16x8*)(&Bs[wc + j * 16 + la][gq * 8]);
#pragma unroll
    for (int i = 0; i < 4; i++)
#pragma unroll
      for (int j = 0; j < 4; j++)
        acc[i][j] = __builtin_amdgcn_mfma_f32_16x16x32_bf16(af[i], bfr[j], acc[i][j], 0, 0, 0);
    __syncthreads();
  }
#pragma unroll
  for (int i = 0; i < 4; i++) {
    int rowb = m0 + wr + i * 16 + gq * 4;
#pragma unroll
    for (int j = 0; j < 4; j++) {
      int col = n0 + wc + j * 16 + la;
      if (col < N) {
#pragma unroll
        for (int r = 0; r < 4; r++)
          C[(size_t)(rowb + r) * ldc + col] = f2bs(acc[i][j][r]);
      }
    }
  }
}

// ---------------------------------------------------------------------------
// depthwise causal conv1d (k=4) + bias + SiLU.
// ---------------------------------------------------------------------------
__global__ __launch_bounds__(256)
void conv_silu(const short* __restrict__ xz, const float* __restrict__ cw,
               const float* __restrict__ cb, short* __restrict__ xs)
{
  const int token = blockIdx.x;
  const int l = token & (L_ - 1);
  const int d0 = threadIdx.x * 8;

  float w[32];
#pragma unroll
  for (int i = 0; i < 8; i++) {
    float4 t = *(const float4*)(cw + (size_t)(d0 + i) * 4);
    w[i * 4 + 0] = t.x; w[i * 4 + 1] = t.y; w[i * 4 + 2] = t.z; w[i * 4 + 3] = t.w;
  }
  float acc[8];
  {
    float4 b0 = *(const float4*)(cb + d0);
    float4 b1 = *(const float4*)(cb + d0 + 4);
    acc[0] = b0.x; acc[1] = b0.y; acc[2] = b0.z; acc[3] = b0.w;
    acc[4] = b1.x; acc[5] = b1.y; acc[6] = b1.z; acc[7] = b1.w;
  }
#pragma unroll
  for (int j = 0; j < 4; j++) {
    int lj = l - 3 + j;
    if (lj >= 0) {
      bf16x8 xv = *(const bf16x8*)(xz + (size_t)(token - 3 + j) * 4096 + d0);
#pragma unroll
      for (int i = 0; i < 8; i++) acc[i] += w[i * 4 + j] * bf2f(xv[i]);
    }
  }
  union { bf16x8 v; short h[8]; } o;
#pragma unroll
  for (int i = 0; i < 8; i++) {
    float v = acc[i];
    o.h[i] = f2bs(v * sigmoidf_fast(v));
  }
  *(bf16x8*)(xs + (size_t)token * DI + d0) = o.v;
}

// ---------------------------------------------------------------------------
// selective scan, 16 lanes per (b,d) channel (one per state n), fused gating.
// Restructured: per 16-step batch, (1) issue all scalar loads, (2) precompute
// dA=exp(dt*An) and w=dt*u*Bn OFF the serial chain, (3) 16 back-to-back chain
// FMAs, (4) DPP row_ror reduction (VALU-rate, no LDS), (5) gate+store lane 0.
// y overwrites the delta cell after consumption (single-owner, race-free).
// ---------------------------------------------------------------------------
__global__ __launch_bounds__(256)
void scan_kernel(short* __restrict__ xz, const short* __restrict__ xs,
                 const short* __restrict__ dbc,
                 const float* __restrict__ A_log, const float* __restrict__ Dw,
                 const float* __restrict__ h0)
{
  const int grp = threadIdx.x >> 4, n = threadIdx.x & 15;
  const int ch = blockIdx.x * 16 + grp;          // ch = b*DI + d
  const int b = ch >> 11, d = ch & (DI - 1);
  const float An = -__expf(A_log[d * NST + n]);
  const float Dd = Dw[d];
  float h = h0[(size_t)ch * NST + n];

  const size_t t0 = (size_t)b * L_;
  const short* dP = xz + t0 * 4096 + d;            // delta cells, stride 4096
  const short* rP = xz + t0 * 4096 + 2048 + d;     // res cells,   stride 4096
  const short* uP = xs + t0 * 2048 + d;            // u cells,     stride 2048
  const short* bP = dbc + t0 * NBC + DTR + n;      // B cells, stride 96; C at +16
  short* yP = xz + t0 * 4096 + d;                  // y over delta cell

  for (int l = 0; l < L_; l += 16) {
    // ---- gather: issue all loads for 16 steps (pipelined by HW) ----
    short dtr[16], ur[16], rr[16], Br[16], Cr[16];
#pragma unroll
    for (int s = 0; s < 16; s++) {
      size_t t = (size_t)(l + s);
      dtr[s] = dP[t * 4096];
      ur[s]  = uP[t * 2048];
      rr[s]  = rP[t * 4096];
      Br[s]  = bP[t * NBC];
      Cr[s]  = bP[t * NBC + 16];
    }
    // ---- precompute (independent of h) ----
    float dA[16], w[16], us[16];
#pragma unroll
    for (int s = 0; s < 16; s++) {
      float dt = bf2f(dtr[s]);
      us[s] = bf2f(ur[s]);
      dA[s] = __expf(dt * An);
      w[s]  = dt * us[s] * bf2f(Br[s]);
    }
    // ---- serial chain (16 FMAs) + p off-chain ----
    float p[16];
#pragma unroll
    for (int s = 0; s < 16; s++) {
      h = __builtin_fmaf(dA[s], h, w[s]);
      p[s] = h * bf2f(Cr[s]);
    }
    // ---- cross-lane reduce over the 16 states (DPP, VALU-rate) ----
#pragma unroll
    for (int s = 0; s < 16; s++) p[s] = rowsum16(p[s]);
    // ---- gate + store, one lane per channel ----
    if (n == 0) {
#pragma unroll
      for (int s = 0; s < 16; s++) {
        float r = bf2f(rr[s]);
        float y = (p[s] + us[s] * Dd) * (r * sigmoidf_fast(r));
        yP[(size_t)(l + s) * 4096] = f2bs(y);
      }
    }
  }
}

// ---------------------------------------------------------------------------
extern "C" void kernel_launch(void* const* d_in, const int* in_sizes, int n_in,
                              void* d_out, int out_size, void* d_ws, size_t ws_size,
                              hipStream_t stream)
{
  const float* u        = (const float*)d_in[0];
  const float* hiddens  = (const float*)d_in[1];
  const float* in_proj  = (const float*)d_in[2];
  const float* conv_w   = (const float*)d_in[3];
  const float* conv_b   = (const float*)d_in[4];
  const float* x_proj   = (const float*)d_in[5];   // (2048, 96)
  const float* dt_proj  = (const float*)d_in[6];   // (64, 2048)
  const float* dt_bias  = (const float*)d_in[7];
  const float* A_log    = (const float*)d_in[8];
  const float* Dw       = (const float*)d_in[9];
  const float* out_proj = (const float*)d_in[10];
  float* out = (float*)d_out;

  // workspace: ~78 MiB total (proven fit)
  char* w = (char*)d_ws;
  short* Wt1  = (short*)w; w += (size_t)4096 * 1024 * 2;   // in_proj^T  (4096 x 1024)
  short* Wxp  = (short*)w; w += (size_t)96   * 2048 * 2;   // x_proj^T   (96 x 2048)
  short* dtw  = (short*)w; w += (size_t)2048 * 64   * 2;   // dt_proj^T  (2048 x 64)
  short* Wt4  = (short*)w; w += (size_t)1024 * 2048 * 2;   // out_proj^T (1024 x 2048)
  short* xz   = (short*)w; w += (size_t)NTOK * 4096 * 2;   // x|res -> delta|res -> y|res
  short* dbc  = (short*)w; w += (size_t)NTOK * NBC  * 2;   // (8192 x 96)
  short* xs   = (short*)d_out;                             // conv out borrows d_out

  dim3 tb(32, 8);
  transpose_f2b<<<dim3(32, 128), tb, 0, stream>>>(in_proj,  Wt1, 1024, 4096, 4096, 1024);
  transpose_f2b<<<dim3(64, 3),   tb, 0, stream>>>(x_proj,   Wxp, 2048, 96,   96,   2048);
  transpose_f2b<<<dim3(2, 64),   tb, 0, stream>>>(dt_proj,  dtw, 64,   2048, 2048, 64);
  transpose_f2b<<<dim3(64, 32),  tb, 0, stream>>>(out_proj, Wt4, 2048, 1024, 1024, 2048);

  // GEMM1: xz = u @ in_proj   (8192 x 4096)
  gemm_a32_bt<<<dim3(64, 32), 256, 0, stream>>>(u, Wt1, xz, 4096, 1024, 1024, 1024, 4096);
  // conv + silu -> xs (token-major, in d_out)
  conv_silu<<<NTOK, 256, 0, stream>>>(xz, conv_w, conv_b, xs);
  // GEMM2: dbc = xs @ x_proj  (8192 x 96)
  gemm_bt<<<dim3(64, 1), 256, 0, stream>>>(xs, Wxp, dbc, nullptr, 96, 2048, 2048, 2048, NBC, 0);
  // GEMM3: delta = softplus(dbc[:, :64] @ dt_proj + bias[col]) -> xz x-half (ldc 4096)
  gemm_bt<<<dim3(64, 16), 256, 0, stream>>>(dbc, dtw, xz, dt_bias, 2048, 64, NBC, 64, 4096, 1);
  // selective scan + gated epilogue: y over delta cells in xz x-half
  scan_kernel<<<512, 256, 0, stream>>>(xz, xs, dbc, A_log, Dw, hiddens);
  // GEMM4: out = y @ out_proj  (8192 x 1024, f32 store)
  gemm_bt<<<dim3(64, 8), 256, 0, stream>>>(xz, Wt4, out, nullptr, 1024, 2048, 4096, 2048, 1024, 2);
}